// Round 2
// baseline (570.300 us; speedup 1.0000x reference)
//
#include <hip/hip_runtime.h>

// GRU cell, B=32768, I=H=512, fp32 in/out, bf16 MFMA internals.
// R2: pre-convert x,h to bf16 A-tiles so BOTH GEMM passes stage A and B via
// global_load_lds (m97 structure) — removes fp32 loads + VALU convert from
// the K-loop (R1 was latency-bound: MfmaUtil 13%, VALUBusy 24%, HBM 39%).
//
// ws layout (bytes):
//   [0,          2621440)   Wzr_t : bf16 B-tiles pass1, 32kt x 8nt x (128x40)
//   [2621440,    3932160)   Whh_t : bf16 B-tiles pass2, 32kt x 4nt x (128x40)
//   [3932160,   87818240)   XHt   : bf16 A-tiles [x|h], 256mt x 32kt x (128x40)
//   [87818240, 129761280)   HRt   : bf16 A-tiles h*r,   256mt x 16kt x (128x40)
//   [129761280,163315712)   Z     : z gate bf16 [32768][512]

#define BATCH 32768
#define HD 512
#define LDT 40                    // padded tile leading dim: 32 data + 8 pad
#define TILE_ELEMS (128 * LDT)    // 5120 elems = 10240 B per tile

typedef __attribute__((ext_vector_type(8))) short short8v;
typedef __attribute__((ext_vector_type(4))) float float4v;

typedef __attribute__((address_space(1))) unsigned int gu32_t;
typedef __attribute__((address_space(3))) unsigned int lu32_t;

__device__ __forceinline__ unsigned short f2bf(float f) {
  unsigned u = __float_as_uint(f);
  u += 0x7fffu + ((u >> 16) & 1u);   // round-to-nearest-even
  return (unsigned short)(u >> 16);
}
__device__ __forceinline__ float bf2f(unsigned short s) {
  return __uint_as_float(((unsigned)s) << 16);
}

__device__ __forceinline__ void async_cp16(const void* g, void* l) {
  __builtin_amdgcn_global_load_lds(
      (gu32_t*)(unsigned long long)g,
      (lu32_t*)(unsigned int)(unsigned long long)l,
      16, 0, 0);
}

__device__ __forceinline__ float fast_sigmoid(float v) {
  return 1.0f / (1.0f + __expf(-v));
}
__device__ __forceinline__ float fast_tanh(float v) {
  float e = __expf(2.0f * v);
  return 1.0f - 2.0f / (e + 1.0f);
}

// ---------------------------------------------------------------------------
// prep: fp32 weights -> bf16 pre-tiled B matrices (pad cols = 0). Unchanged R1.
// ---------------------------------------------------------------------------
__global__ __launch_bounds__(256) void prep_weights(
    const float* __restrict__ Wz, const float* __restrict__ Wr,
    const float* __restrict__ Uz, const float* __restrict__ Ur,
    const float* __restrict__ Wh, const float* __restrict__ Uh,
    unsigned short* __restrict__ Wzr_t, unsigned short* __restrict__ Whh_t) {
  int e = blockIdx.x * 256 + threadIdx.x;
  if (e < 32 * 8 * TILE_ELEMS) {
    int tile = e / TILE_ELEMS;
    int rem  = e % TILE_ELEMS;
    int r = rem / LDT, c = rem % LDT;
    int kt = tile >> 3, nt = tile & 7;
    float v = 0.0f;
    if (c < 32) {
      int n = nt * 128 + r;     // 0..1023
      int k = kt * 32 + c;      // 0..1023
      int nn = (n < 512) ? n : (n - 512);
      if (k < 512) v = (n < 512) ? Wz[nn * 512 + k] : Wr[nn * 512 + k];
      else         v = (n < 512) ? Uz[nn * 512 + (k - 512)] : Ur[nn * 512 + (k - 512)];
    }
    Wzr_t[e] = f2bf(v);
  } else {
    int e2 = e - 32 * 8 * TILE_ELEMS;
    if (e2 < 32 * 4 * TILE_ELEMS) {
      int tile = e2 / TILE_ELEMS;
      int rem  = e2 % TILE_ELEMS;
      int r = rem / LDT, c = rem % LDT;
      int kt = tile >> 2;
      int nt = tile & 3;
      float v = 0.0f;
      if (c < 32) {
        int n = nt * 128 + r;   // 0..511
        int k = kt * 32 + c;    // 0..1023
        v = (k < 512) ? Wh[n * 512 + k] : Uh[n * 512 + (k - 512)];
      }
      Whh_t[e2] = f2bf(v);
    }
  }
}

// ---------------------------------------------------------------------------
// conv_xh: x,h fp32 -> bf16 A-tiles. One thread per tile-row (40 elems, 80B,
// 16B-aligned since 80 = 5*16). Rows are contiguous in XHt -> coalesced writes.
// rows total = 256mt * 32kt * 128 = 1,048,576 = 4096 blocks x 256.
// ---------------------------------------------------------------------------
__global__ __launch_bounds__(256) void conv_xh(
    const float* __restrict__ x, const float* __restrict__ h,
    unsigned short* __restrict__ XHt) {
  int row = blockIdx.x * 256 + threadIdx.x;
  int r = row & 127;
  int tileIdx = row >> 7;          // mt*32 + kt
  int kt = tileIdx & 31;
  int mt = tileIdx >> 5;
  int m = mt * 128 + r;
  const float* src = (kt < 16) ? (x + (size_t)m * HD + kt * 32)
                               : (h + (size_t)m * HD + (kt - 16) * 32);
  unsigned short* dst = XHt + (size_t)tileIdx * TILE_ELEMS + r * LDT;

  unsigned short t[32];
#pragma unroll
  for (int i = 0; i < 8; ++i) {
    float4 v = ((const float4*)src)[i];
    t[i * 4 + 0] = f2bf(v.x); t[i * 4 + 1] = f2bf(v.y);
    t[i * 4 + 2] = f2bf(v.z); t[i * 4 + 3] = f2bf(v.w);
  }
#pragma unroll
  for (int j = 0; j < 4; ++j) {
    short8v s;
#pragma unroll
    for (int q = 0; q < 8; ++q) s[q] = (short)t[j * 8 + q];
    *(short8v*)(dst + j * 8) = s;
  }
  short8v zz = (short8v)0;
  *(short8v*)(dst + 32) = zz;      // pad cols 32..39
}

// ---------------------------------------------------------------------------
// shared GEMM building blocks: 128x128 block tile, BK=32, 4 waves (2x2 of 64x64)
// ---------------------------------------------------------------------------
__device__ __forceinline__ void stage_tile_async(const unsigned short* __restrict__ tile,
                                                 unsigned short* lds, int wave, int lane) {
  const char* gt = (const char*)tile;
  char* lt = (char*)lds;
  int off0 = wave * 2048 + lane * 16;
  async_cp16(gt + off0, lt + off0);
  async_cp16(gt + off0 + 1024, lt + off0 + 1024);
  if (wave < 2) {
    int off2 = 8192 + wave * 1024 + lane * 16;
    async_cp16(gt + off2, lt + off2);
  }
}

__device__ __forceinline__ void mfma_step(const unsigned short* Alds,
                                          const unsigned short* Blds,
                                          float4v acc[4][4],
                                          int wm, int wn, int quad, int l16) {
  short8v a[4], b[4];
#pragma unroll
  for (int i = 0; i < 4; ++i)
    a[i] = *(const short8v*)(Alds + (wm + i * 16 + l16) * LDT + quad * 8);
#pragma unroll
  for (int j = 0; j < 4; ++j)
    b[j] = *(const short8v*)(Blds + (wn + j * 16 + l16) * LDT + quad * 8);
#pragma unroll
  for (int i = 0; i < 4; ++i)
#pragma unroll
    for (int j = 0; j < 4; ++j)
      acc[i][j] = __builtin_amdgcn_mfma_f32_16x16x32_bf16(a[i], b[j], acc[i][j], 0, 0, 0);
}

// ---------------------------------------------------------------------------
// pass 1: pre_zr = [x|h] @ B1 ; z = sigmoid -> Z ; r = sigmoid -> HRt = bf16(h*r)
// grid (8, 256): x = nt (0..3 z, 4..7 r), y = mt. All staging async.
// ---------------------------------------------------------------------------
__global__ __launch_bounds__(256) void gemm_zr(
    const float* __restrict__ h,
    const unsigned short* __restrict__ XHt,
    const unsigned short* __restrict__ Wt,
    const float* __restrict__ Wz_b, const float* __restrict__ Uz_b,
    const float* __restrict__ Wr_b, const float* __restrict__ Ur_b,
    unsigned short* __restrict__ Z, unsigned short* __restrict__ HRt) {
  __shared__ __align__(16) unsigned short Alds[128 * LDT];
  __shared__ __align__(16) unsigned short Blds[128 * LDT];
  const int tid = threadIdx.x;
  const int wave = tid >> 6, lane = tid & 63;
  const int quad = lane >> 4, l16 = lane & 15;
  const int nt = blockIdx.x;   // 0..7
  const int mt = blockIdx.y;   // 0..255
  const int m0 = mt * 128;
  const int wm = (wave >> 1) * 64, wn = (wave & 1) * 64;

  float4v acc[4][4] = {};

  for (int kt = 0; kt < 32; ++kt) {
    stage_tile_async(Wt + (size_t)(kt * 8 + nt) * TILE_ELEMS, Blds, wave, lane);
    stage_tile_async(XHt + (size_t)(mt * 32 + kt) * TILE_ELEMS, Alds, wave, lane);
    __syncthreads();
    mfma_step(Alds, Blds, acc, wm, wn, quad, l16);
    __syncthreads();
  }

  const int n0 = nt * 128;
  if (n0 < 512) {
    // z gate
#pragma unroll
    for (int j = 0; j < 4; ++j) {
      int n = n0 + wn + j * 16 + l16;
      float bias = Wz_b[n] + Uz_b[n];
#pragma unroll
      for (int i = 0; i < 4; ++i) {
#pragma unroll
        for (int reg = 0; reg < 4; ++reg) {
          int m = m0 + wm + i * 16 + quad * 4 + reg;
          float v = fast_sigmoid(acc[i][j][reg] + bias);
          Z[(size_t)m * HD + n] = f2bf(v);
        }
      }
    }
  } else {
    // r gate -> hr = h*r, stored pre-tiled as pass-2 A tiles
#pragma unroll
    for (int j = 0; j < 4; ++j) {
      int nn = (n0 - 512) + wn + j * 16 + l16;   // 0..511
      float bias = Wr_b[nn] + Ur_b[nn];
      int ktile = nn >> 5, kc = nn & 31;
#pragma unroll
      for (int i = 0; i < 4; ++i) {
#pragma unroll
        for (int reg = 0; reg < 4; ++reg) {
          int m = m0 + wm + i * 16 + quad * 4 + reg;
          float rv = fast_sigmoid(acc[i][j][reg] + bias);
          float hv = h[(size_t)m * HD + nn];
          HRt[(size_t)(mt * 16 + ktile) * TILE_ELEMS + (m & 127) * LDT + kc] = f2bf(hv * rv);
        }
      }
    }
  }
}

// ---------------------------------------------------------------------------
// pass 2: pre_h = [x|hr] @ B2 ; ht = tanh ; h_next = h + z*(ht - h) -> out x2
// grid (4, 256). A: kt<16 -> x half of XHt; kt>=16 -> HRt. All staging async.
// ---------------------------------------------------------------------------
__global__ __launch_bounds__(256) void gemm_out(
    const float* __restrict__ h,
    const unsigned short* __restrict__ XHt,
    const unsigned short* __restrict__ Wt,
    const float* __restrict__ Wh_b, const float* __restrict__ Uh_b,
    const unsigned short* __restrict__ Z, const unsigned short* __restrict__ HRt,
    float* __restrict__ out) {
  __shared__ __align__(16) unsigned short Alds[128 * LDT];
  __shared__ __align__(16) unsigned short Blds[128 * LDT];
  const int tid = threadIdx.x;
  const int wave = tid >> 6, lane = tid & 63;
  const int quad = lane >> 4, l16 = lane & 15;
  const int nt = blockIdx.x;   // 0..3
  const int mt = blockIdx.y;   // 0..255
  const int m0 = mt * 128;
  const int wm = (wave >> 1) * 64, wn = (wave & 1) * 64;

  float4v acc[4][4] = {};

  for (int kt = 0; kt < 32; ++kt) {
    stage_tile_async(Wt + (size_t)(kt * 4 + nt) * TILE_ELEMS, Blds, wave, lane);
    const unsigned short* At = (kt < 16)
        ? (XHt + (size_t)(mt * 32 + kt) * TILE_ELEMS)
        : (HRt + (size_t)(mt * 16 + (kt - 16)) * TILE_ELEMS);
    stage_tile_async(At, Alds, wave, lane);
    __syncthreads();
    mfma_step(Alds, Blds, acc, wm, wn, quad, l16);
    __syncthreads();
  }

  const int n0 = nt * 128;
#pragma unroll
  for (int j = 0; j < 4; ++j) {
    int n = n0 + wn + j * 16 + l16;
    float bias = Wh_b[n] + Uh_b[n];
#pragma unroll
    for (int i = 0; i < 4; ++i) {
#pragma unroll
      for (int reg = 0; reg < 4; ++reg) {
        int m = m0 + wm + i * 16 + quad * 4 + reg;
        size_t idx = (size_t)m * HD + n;
        float ht = fast_tanh(acc[i][j][reg] + bias);
        float hv = h[idx];
        float zv = bf2f(Z[idx]);
        float o = fmaf(zv, ht - hv, hv);
        out[idx] = o;
        out[(size_t)BATCH * HD + idx] = o;
      }
    }
  }
}

// ---------------------------------------------------------------------------
extern "C" void kernel_launch(void* const* d_in, const int* in_sizes, int n_in,
                              void* d_out, int out_size, void* d_ws, size_t ws_size,
                              hipStream_t stream) {
  const float* x    = (const float*)d_in[0];
  const float* h    = (const float*)d_in[1];
  const float* Wz_w = (const float*)d_in[2];
  const float* Wz_b = (const float*)d_in[3];
  const float* Wr_w = (const float*)d_in[4];
  const float* Wr_b = (const float*)d_in[5];
  const float* Wh_w = (const float*)d_in[6];
  const float* Wh_b = (const float*)d_in[7];
  const float* Uz_w = (const float*)d_in[8];
  const float* Uz_b = (const float*)d_in[9];
  const float* Ur_w = (const float*)d_in[10];
  const float* Ur_b = (const float*)d_in[11];
  const float* Uh_w = (const float*)d_in[12];
  const float* Uh_b = (const float*)d_in[13];
  float* out = (float*)d_out;

  char* ws = (char*)d_ws;
  unsigned short* Wzr_t = (unsigned short*)(ws);               //  2,621,440 B
  unsigned short* Whh_t = (unsigned short*)(ws + 2621440);     //  1,310,720 B
  unsigned short* XHt   = (unsigned short*)(ws + 3932160);     // 83,886,080 B
  unsigned short* HRt   = (unsigned short*)(ws + 87818240);    // 41,943,040 B
  unsigned short* Z     = (unsigned short*)(ws + 129761280);   // 33,554,432 B

  prep_weights<<<7680, 256, 0, stream>>>(Wz_w, Wr_w, Uz_w, Ur_w, Wh_w, Uh_w, Wzr_t, Whh_t);
  conv_xh<<<4096, 256, 0, stream>>>(x, h, XHt);
  gemm_zr<<<dim3(8, 256), 256, 0, stream>>>(h, XHt, Wzr_t, Wz_b, Uz_b, Wr_b, Ur_b, Z, HRt);
  gemm_out<<<dim3(4, 256), 256, 0, stream>>>(h, XHt, Whh_t, Wh_b, Uh_b, Z, HRt, out);
}

// Round 3
// 532.949 us; speedup vs baseline: 1.0701x; 1.0701x over previous
//
#include <hip/hip_runtime.h>

// GRU cell, B=32768, I=H=512, fp32 in/out, bf16 MFMA internals.
// R3: software-pipelined K-loop (double-buffered LDS stage, raw s_barrier +
// s_waitcnt vmcnt(5) — no full drain), XCD-aware block swizzle for A-tile L2
// reuse, coalesced conv merged with weight prep.
//
// ws layout (bytes):
//   [0,          2621440)   Wzr_t : bf16 B-tiles pass1, 32kt x 8nt x (128x40)
//   [2621440,    3932160)   Whh_t : bf16 B-tiles pass2, 32kt x 4nt x (128x40)
//   [3932160,   87818240)   XHt   : bf16 A-tiles [x|h], 256mt x 32kt x (128x40)
//   [87818240, 129761280)   HRt   : bf16 A-tiles h*r,   256mt x 16kt x (128x40)
//   [129761280,163315712)   Z     : z gate bf16 [32768][512]

#define BATCH 32768
#define HD 512
#define LDT 40                    // padded tile leading dim: 32 data + 8 pad
#define TILE_ELEMS (128 * LDT)    // 5120 elems = 10240 B per tile
#define STAGE_SHORTS (2 * TILE_ELEMS)  // [B tile | A tile] = 20480 B

typedef __attribute__((ext_vector_type(8))) short short8v;
typedef __attribute__((ext_vector_type(4))) float float4v;

typedef __attribute__((address_space(1))) unsigned int gu32_t;
typedef __attribute__((address_space(3))) unsigned int lu32_t;

__device__ __forceinline__ unsigned short f2bf(float f) {
  unsigned u = __float_as_uint(f);
  u += 0x7fffu + ((u >> 16) & 1u);   // round-to-nearest-even
  return (unsigned short)(u >> 16);
}
__device__ __forceinline__ float bf2f(unsigned short s) {
  return __uint_as_float(((unsigned)s) << 16);
}

// async 16B/lane global->LDS DMA. g is per-lane address, l is wave-uniform.
__device__ __forceinline__ void async_cp16(const void* g, void* l) {
  __builtin_amdgcn_global_load_lds(
      (gu32_t*)(unsigned long long)g,
      (lu32_t*)(unsigned int)(unsigned long long)l,
      16, 0, 0);
}

__device__ __forceinline__ float fast_sigmoid(float v) {
  return 1.0f / (1.0f + __expf(-v));
}
__device__ __forceinline__ float fast_tanh(float v) {
  float e = __expf(2.0f * v);
  return 1.0f - 2.0f / (e + 1.0f);
}

// ---------------------------------------------------------------------------
// prep_all: blocks [0,8192) convert x,h -> XHt bf16 A-tiles (coalesced);
//           blocks [8192,15872) scatter fp32 weights -> bf16 B-tiles.
// ---------------------------------------------------------------------------
__global__ __launch_bounds__(256) void prep_all(
    const float* __restrict__ x, const float* __restrict__ h,
    const float* __restrict__ Wz, const float* __restrict__ Wr,
    const float* __restrict__ Uz, const float* __restrict__ Ur,
    const float* __restrict__ Wh, const float* __restrict__ Uh,
    unsigned short* __restrict__ XHt,
    unsigned short* __restrict__ Wzr_t, unsigned short* __restrict__ Whh_t) {
  int b = blockIdx.x;
  int t = threadIdx.x;
  if (b < 8192) {
    // conv: one 128x32 tile per block, coalesced float4 reads
    int kt = b & 31, mt = b >> 5;
    const float* src = (kt < 16)
        ? (x + (size_t)(mt * 128) * HD + kt * 32)
        : (h + (size_t)(mt * 128) * HD + (kt - 16) * 32);
    unsigned short* dst = XHt + (size_t)b * TILE_ELEMS;
    int r0 = t >> 3, c0 = (t & 7) * 4;
#pragma unroll
    for (int it = 0; it < 4; ++it) {
      int r = r0 + it * 32;
      float4 v = *(const float4*)(src + (size_t)r * HD + c0);
      short4 s;
      s.x = (short)f2bf(v.x); s.y = (short)f2bf(v.y);
      s.z = (short)f2bf(v.z); s.w = (short)f2bf(v.w);
      *(short4*)(dst + r * LDT + c0) = s;
    }
    if (t < 128) {               // zero the 8-short pad of each row
      short8v zz = (short8v)0;
      *(short8v*)(dst + t * LDT + 32) = zz;
    }
  } else {
    int e = (b - 8192) * 256 + t;
    if (e < 32 * 8 * TILE_ELEMS) {
      int tile = e / TILE_ELEMS;
      int rem  = e % TILE_ELEMS;
      int r = rem / LDT, c = rem % LDT;
      int kt = tile >> 3, nt = tile & 7;
      float v = 0.0f;
      if (c < 32) {
        int n = nt * 128 + r;     // 0..1023
        int k = kt * 32 + c;      // 0..1023
        int nn = (n < 512) ? n : (n - 512);
        if (k < 512) v = (n < 512) ? Wz[nn * 512 + k] : Wr[nn * 512 + k];
        else         v = (n < 512) ? Uz[nn * 512 + (k - 512)] : Ur[nn * 512 + (k - 512)];
      }
      Wzr_t[e] = f2bf(v);
    } else {
      int e2 = e - 32 * 8 * TILE_ELEMS;
      if (e2 < 32 * 4 * TILE_ELEMS) {
        int tile = e2 / TILE_ELEMS;
        int rem  = e2 % TILE_ELEMS;
        int r = rem / LDT, c = rem % LDT;
        int kt = tile >> 2, nt = tile & 3;
        float v = 0.0f;
        if (c < 32) {
          int n = nt * 128 + r;   // 0..511
          int k = kt * 32 + c;    // 0..1023
          v = (k < 512) ? Wh[n * 512 + k] : Uh[n * 512 + (k - 512)];
        }
        Whh_t[e2] = f2bf(v);
      }
    }
  }
}

// ---------------------------------------------------------------------------
// pipelined staging: stage = [B tile (10240 B) | A tile (10240 B)], each wave
// issues exactly 5 x 1KB DMAs: waves 0-1 cover B, waves 2-3 cover A.
// ---------------------------------------------------------------------------
__device__ __forceinline__ void prefetch_pair(const unsigned short* __restrict__ Bt,
                                              const unsigned short* __restrict__ At,
                                              unsigned short* stage,
                                              int wave, int lane) {
  const char* gb = (wave < 2) ? ((const char*)Bt + wave * 5120)
                              : ((const char*)At + (wave - 2) * 5120);
  char* lb = (char*)stage + wave * 5120;
#pragma unroll
  for (int i = 0; i < 5; ++i)
    async_cp16(gb + i * 1024 + lane * 16, lb + i * 1024);
}

__device__ __forceinline__ void mfma_step(const unsigned short* stage,
                                          float4v acc[4][4],
                                          int wm, int wn, int quad, int l16) {
  const unsigned short* Blds = stage;               // B tile at offset 0
  const unsigned short* Alds = stage + TILE_ELEMS;  // A tile at +10240 B
  short8v a[4], b[4];
#pragma unroll
  for (int i = 0; i < 4; ++i)
    a[i] = *(const short8v*)(Alds + (wm + i * 16 + l16) * LDT + quad * 8);
#pragma unroll
  for (int j = 0; j < 4; ++j)
    b[j] = *(const short8v*)(Blds + (wn + j * 16 + l16) * LDT + quad * 8);
#pragma unroll
  for (int i = 0; i < 4; ++i)
#pragma unroll
    for (int j = 0; j < 4; ++j)
      acc[i][j] = __builtin_amdgcn_mfma_f32_16x16x32_bf16(a[i], b[j], acc[i][j], 0, 0, 0);
}

#define WAIT_VM5()  asm volatile("s_waitcnt vmcnt(5)" ::: "memory")
#define WAIT_VM0()  asm volatile("s_waitcnt vmcnt(0)" ::: "memory")
#define RAW_BAR()   asm volatile("s_barrier" ::: "memory")

// ---------------------------------------------------------------------------
// pass 1: pre_zr = [x|h] @ B1 ; z = sigmoid -> Z ; r -> HRt = bf16(h*r)
// grid 2048 linear; swizzle: xcd=b&7, q=b>>3, nt=q&7, mt=(b&7)*32+(q>>3)
// so all 8 nt-blocks of an mt land on one XCD (A-tile L2 reuse).
// ---------------------------------------------------------------------------
__global__ __launch_bounds__(256, 3) void gemm_zr(
    const float* __restrict__ h,
    const unsigned short* __restrict__ XHt,
    const unsigned short* __restrict__ Wt,
    const float* __restrict__ Wz_b, const float* __restrict__ Uz_b,
    const float* __restrict__ Wr_b, const float* __restrict__ Ur_b,
    unsigned short* __restrict__ Z, unsigned short* __restrict__ HRt) {
  __shared__ __align__(16) unsigned short Stg[2][STAGE_SHORTS];
  const int tid = threadIdx.x;
  const int wave = tid >> 6, lane = tid & 63;
  const int quad = lane >> 4, l16 = lane & 15;
  const int b = blockIdx.x;
  const int q = b >> 3;
  const int nt = q & 7;                   // 0..7
  const int mt = (b & 7) * 32 + (q >> 3); // 0..255
  const int m0 = mt * 128;
  const int wm = (wave >> 1) * 64, wn = (wave & 1) * 64;

  float4v acc[4][4] = {};

  prefetch_pair(Wt + (size_t)(0 * 8 + nt) * TILE_ELEMS,
                XHt + (size_t)(mt * 32 + 0) * TILE_ELEMS, Stg[0], wave, lane);
  for (int kt = 0; kt < 32; ++kt) {
    if (kt < 31) {
      prefetch_pair(Wt + (size_t)((kt + 1) * 8 + nt) * TILE_ELEMS,
                    XHt + (size_t)(mt * 32 + kt + 1) * TILE_ELEMS,
                    Stg[(kt + 1) & 1], wave, lane);
      WAIT_VM5();
    } else {
      WAIT_VM0();
    }
    RAW_BAR();
    mfma_step(Stg[kt & 1], acc, wm, wn, quad, l16);
    RAW_BAR();
  }

  const int n0 = nt * 128;
  if (n0 < 512) {
    // z gate
#pragma unroll
    for (int j = 0; j < 4; ++j) {
      int n = n0 + wn + j * 16 + l16;
      float bias = Wz_b[n] + Uz_b[n];
#pragma unroll
      for (int i = 0; i < 4; ++i) {
#pragma unroll
        for (int reg = 0; reg < 4; ++reg) {
          int m = m0 + wm + i * 16 + quad * 4 + reg;
          float v = fast_sigmoid(acc[i][j][reg] + bias);
          Z[(size_t)m * HD + n] = f2bf(v);
        }
      }
    }
  } else {
    // r gate -> hr = h*r, stored pre-tiled as pass-2 A tiles
#pragma unroll
    for (int j = 0; j < 4; ++j) {
      int nn = (n0 - 512) + wn + j * 16 + l16;   // 0..511
      float bias = Wr_b[nn] + Ur_b[nn];
      int ktile = nn >> 5, kc = nn & 31;
#pragma unroll
      for (int i = 0; i < 4; ++i) {
#pragma unroll
        for (int reg = 0; reg < 4; ++reg) {
          int m = m0 + wm + i * 16 + quad * 4 + reg;
          float rv = fast_sigmoid(acc[i][j][reg] + bias);
          float hv = h[(size_t)m * HD + nn];
          HRt[(size_t)(mt * 16 + ktile) * TILE_ELEMS + (m & 127) * LDT + kc] = f2bf(hv * rv);
        }
      }
    }
  }
}

// ---------------------------------------------------------------------------
// pass 2: pre_h = [x|hr] @ B2 ; ht = tanh ; h_next = h + z*(ht - h) -> out x2
// grid 1024 linear; swizzle: xcd=b&7, q=b>>3, nt=q&3, mt=(b&7)*32+(q>>2)
// ---------------------------------------------------------------------------
__global__ __launch_bounds__(256, 3) void gemm_out(
    const float* __restrict__ h,
    const unsigned short* __restrict__ XHt,
    const unsigned short* __restrict__ Wt,
    const float* __restrict__ Wh_b, const float* __restrict__ Uh_b,
    const unsigned short* __restrict__ Z, const unsigned short* __restrict__ HRt,
    float* __restrict__ out) {
  __shared__ __align__(16) unsigned short Stg[2][STAGE_SHORTS];
  const int tid = threadIdx.x;
  const int wave = tid >> 6, lane = tid & 63;
  const int quad = lane >> 4, l16 = lane & 15;
  const int b = blockIdx.x;
  const int q = b >> 3;
  const int nt = q & 3;                   // 0..3
  const int mt = (b & 7) * 32 + (q >> 2); // 0..255
  const int m0 = mt * 128;
  const int wm = (wave >> 1) * 64, wn = (wave & 1) * 64;

  float4v acc[4][4] = {};

  const unsigned short* A0 = XHt + (size_t)(mt * 32) * TILE_ELEMS;
  prefetch_pair(Wt + (size_t)nt * TILE_ELEMS, A0, Stg[0], wave, lane);
  for (int kt = 0; kt < 32; ++kt) {
    if (kt < 31) {
      int kn = kt + 1;
      const unsigned short* At = (kn < 16)
          ? (XHt + (size_t)(mt * 32 + kn) * TILE_ELEMS)
          : (HRt + (size_t)(mt * 16 + (kn - 16)) * TILE_ELEMS);
      prefetch_pair(Wt + (size_t)(kn * 4 + nt) * TILE_ELEMS, At,
                    Stg[kn & 1], wave, lane);
      WAIT_VM5();
    } else {
      WAIT_VM0();
    }
    RAW_BAR();
    mfma_step(Stg[kt & 1], acc, wm, wn, quad, l16);
    RAW_BAR();
  }

  const int n0 = nt * 128;
#pragma unroll
  for (int j = 0; j < 4; ++j) {
    int n = n0 + wn + j * 16 + l16;
    float bias = Wh_b[n] + Uh_b[n];
#pragma unroll
    for (int i = 0; i < 4; ++i) {
#pragma unroll
      for (int reg = 0; reg < 4; ++reg) {
        int m = m0 + wm + i * 16 + quad * 4 + reg;
        size_t idx = (size_t)m * HD + n;
        float ht = fast_tanh(acc[i][j][reg] + bias);
        float hv = h[idx];
        float zv = bf2f(Z[idx]);
        float o = fmaf(zv, ht - hv, hv);
        out[idx] = o;
        out[(size_t)BATCH * HD + idx] = o;
      }
    }
  }
}

// ---------------------------------------------------------------------------
extern "C" void kernel_launch(void* const* d_in, const int* in_sizes, int n_in,
                              void* d_out, int out_size, void* d_ws, size_t ws_size,
                              hipStream_t stream) {
  const float* x    = (const float*)d_in[0];
  const float* h    = (const float*)d_in[1];
  const float* Wz_w = (const float*)d_in[2];
  const float* Wz_b = (const float*)d_in[3];
  const float* Wr_w = (const float*)d_in[4];
  const float* Wr_b = (const float*)d_in[5];
  const float* Wh_w = (const float*)d_in[6];
  const float* Wh_b = (const float*)d_in[7];
  const float* Uz_w = (const float*)d_in[8];
  const float* Uz_b = (const float*)d_in[9];
  const float* Ur_w = (const float*)d_in[10];
  const float* Ur_b = (const float*)d_in[11];
  const float* Uh_w = (const float*)d_in[12];
  const float* Uh_b = (const float*)d_in[13];
  float* out = (float*)d_out;

  char* ws = (char*)d_ws;
  unsigned short* Wzr_t = (unsigned short*)(ws);               //  2,621,440 B
  unsigned short* Whh_t = (unsigned short*)(ws + 2621440);     //  1,310,720 B
  unsigned short* XHt   = (unsigned short*)(ws + 3932160);     // 83,886,080 B
  unsigned short* HRt   = (unsigned short*)(ws + 87818240);    // 41,943,040 B
  unsigned short* Z     = (unsigned short*)(ws + 129761280);   // 33,554,432 B

  prep_all<<<15872, 256, 0, stream>>>(x, h, Wz_w, Wr_w, Uz_w, Ur_w, Wh_w, Uh_w,
                                      XHt, Wzr_t, Whh_t);
  gemm_zr<<<2048, 256, 0, stream>>>(h, XHt, Wzr_t, Wz_b, Uz_b, Wr_b, Ur_b, Z, HRt);
  gemm_out<<<1024, 256, 0, stream>>>(h, XHt, Whh_t, Wh_b, Uh_b, Z, HRt, out);
}